// Round 1
// baseline (216.372 us; speedup 1.0000x reference)
//
#include <hip/hip_runtime.h>
#include <hip/hip_bf16.h>

typedef __attribute__((ext_vector_type(8))) short short8;   // 8 bf16 (4 VGPRs) MFMA A/B frag
typedef __attribute__((ext_vector_type(4))) float f32x4;    // MFMA C/D frag

constexpr int B_ROWS   = 524288;
constexpr int ROWTILES = B_ROWS / 64;   // 8192 blocks of 64 rows

// tanh(x) = 1 - 2/(exp2(2*log2(e)*x) + 1); saturates correctly for large |x|
__device__ __forceinline__ float fast_tanh(float x) {
  float e = __builtin_amdgcn_exp2f(x * 2.8853900817779268f);
  return 1.0f - 2.0f * __builtin_amdgcn_rcpf(e + 1.0f);
}

__device__ __forceinline__ short bf16_rne(float f) {
  union { float f; unsigned u; } v; v.f = f;
  unsigned u = v.u + 0x7FFFu + ((v.u >> 16) & 1u);
  return (short)(u >> 16);
}

__device__ __forceinline__ short8 pack8(f32x4 a, f32x4 b) {
  short8 f;
  f[0] = bf16_rne(a[0]); f[1] = bf16_rne(a[1]);
  f[2] = bf16_rne(a[2]); f[3] = bf16_rne(a[3]);
  f[4] = bf16_rne(b[0]); f[5] = bf16_rne(b[1]);
  f[6] = bf16_rne(b[2]); f[7] = bf16_rne(b[3]);
  return f;
}

// Transposed-orientation fused kernel:
//   C[n, b] = sum_i W1[n, i] * x[b, i]   (n = k*32+h, 256 total)
//   out[b, k] = (tanh(sum_h tanh(C + b1)*W2 + b2) + 1) * 0.5
// Wave w owns n in [64w, 64w+64) -> classifiers {2w, 2w+1}; weights in registers.
__global__ __launch_bounds__(256, 4) void fused_mlp8(
    const float* __restrict__ x, const float* __restrict__ W1,
    const float* __restrict__ b1, const float* __restrict__ W2,
    const float* __restrict__ b2, float* __restrict__ out) {

  // x chunks in fragment order: [tile(4)][kstep(2)][lane(64)] of 16B
  __shared__ short8 xch[512];

  const int tid  = threadIdx.x;
  const int wave = tid >> 6;
  const int lane = tid & 63;
  const int m16  = lane & 15;   // MFMA M-row / C-col index
  const int q    = lane >> 4;   // quad

  // ---- preload W1 A-fragments: lane holds W1[n=(4w+mt)*16+m16][ks*32+q*8 .. +7]
  short8 w1f[4][2];
#pragma unroll
  for (int mt = 0; mt < 4; ++mt) {
    const int n = (wave * 4 + mt) * 16 + m16;
#pragma unroll
    for (int ks = 0; ks < 2; ++ks) {
      const float* p = W1 + n * 64 + ks * 32 + q * 8;
      w1f[mt][ks] = pack8(*(const f32x4*)p, *(const f32x4*)(p + 4));
    }
  }

  // ---- per-lane b1/W2 for the n's this lane holds in C-layout: n0 = 16*(4w+mt) + 4q
  f32x4 b1v[4], w2v[4];
#pragma unroll
  for (int mt = 0; mt < 4; ++mt) {
    const int n0 = (wave * 4 + mt) * 16 + q * 4;
    b1v[mt] = *(const f32x4*)(b1 + n0);
    w2v[mt] = *(const f32x4*)(W2 + n0);
  }
  const float b2v[2] = { b2[wave * 2], b2[wave * 2 + 1] };

  for (int it = blockIdx.x; it < ROWTILES; it += gridDim.x) {
    const long base = (long)it * 64;

    // ---- stage 64 rows of x -> LDS bf16 chunks (each thread: 2 chunks of 8 floats)
#pragma unroll
    for (int cc = 0; cc < 2; ++cc) {
      const int c   = tid * 2 + cc;
      const int tt  = c >> 7;
      const int ks  = (c >> 6) & 1;
      const int cl  = c & 63;
      const int row = tt * 16 + (cl & 15);
      const int col = ks * 32 + (cl >> 4) * 8;
      const float* p = x + (base + row) * 64 + col;
      xch[c] = pack8(*(const f32x4*)p, *(const f32x4*)(p + 4));
    }
    __syncthreads();

#pragma unroll
    for (int tt = 0; tt < 4; ++tt) {
      const short8 xf0 = xch[(tt * 2 + 0) * 64 + lane];
      const short8 xf1 = xch[(tt * 2 + 1) * 64 + lane];

      f32x4 acc[4];
#pragma unroll
      for (int mt = 0; mt < 4; ++mt) {
        f32x4 z = { 0.f, 0.f, 0.f, 0.f };
        z = __builtin_amdgcn_mfma_f32_16x16x32_bf16(w1f[mt][0], xf0, z, 0, 0, 0);
        z = __builtin_amdgcn_mfma_f32_16x16x32_bf16(w1f[mt][1], xf1, z, 0, 0, 0);
        acc[mt] = z;
      }

      // ---- stage 2: per k (j=0,1), sum over this lane's 8 h-values then 2 shuffles
      float o0 = 0.f, o1 = 0.f;
#pragma unroll
      for (int j = 0; j < 2; ++j) {
        float S = 0.f;
#pragma unroll
        for (int t = 0; t < 2; ++t) {
          const int mt = j * 2 + t;
#pragma unroll
          for (int r = 0; r < 4; ++r)
            S += fast_tanh(acc[mt][r] + b1v[mt][r]) * w2v[mt][r];
        }
        S += __shfl_xor(S, 16);
        S += __shfl_xor(S, 32);
        const float o = 0.5f * fast_tanh(S + b2v[j]) + 0.5f;
        if (j == 0) o0 = o; else o1 = o;
      }

      if (q == 0) {  // 16 lanes write float2 {k=2w, k=2w+1} for rows tt*16+m16
        float2 st; st.x = o0; st.y = o1;
        *(float2*)(out + (base + tt * 16 + m16) * 8 + wave * 2) = st;
      }
    }
    __syncthreads();
  }
}

extern "C" void kernel_launch(void* const* d_in, const int* in_sizes, int n_in,
                              void* d_out, int out_size, void* d_ws, size_t ws_size,
                              hipStream_t stream) {
  const float* x  = (const float*)d_in[0];
  const float* W1 = (const float*)d_in[1];
  const float* b1 = (const float*)d_in[2];
  const float* W2 = (const float*)d_in[3];
  const float* b2 = (const float*)d_in[4];
  float* out = (float*)d_out;
  fused_mlp8<<<1024, 256, 0, stream>>>(x, W1, b1, W2, b2, out);
}

// Round 2
// 216.176 us; speedup vs baseline: 1.0009x; 1.0009x over previous
//
#include <hip/hip_runtime.h>
#include <hip/hip_bf16.h>

typedef __attribute__((ext_vector_type(8))) short short8;   // 8 bf16 (4 VGPRs) MFMA A/B frag
typedef __attribute__((ext_vector_type(4))) float f32x4;    // MFMA C/D frag

constexpr int B_ROWS   = 524288;
constexpr int ROWTILES = B_ROWS / 64;   // 8192 tiles of 64 rows
constexpr int GRID     = 2048;          // 4 grid-stride iters per block
constexpr float L2E2   = 2.8853900817779268f;  // 2*log2(e)

__device__ __forceinline__ short bf16_rne(float f) {
  union { float f; unsigned u; } v; v.f = f;
  unsigned u = v.u + 0x7FFFu + ((v.u >> 16) & 1u);
  return (short)(u >> 16);
}

__device__ __forceinline__ short8 pack8(f32x4 a, f32x4 b) {
  short8 f;
  f[0] = bf16_rne(a[0]); f[1] = bf16_rne(a[1]);
  f[2] = bf16_rne(a[2]); f[3] = bf16_rne(a[3]);
  f[4] = bf16_rne(b[0]); f[5] = bf16_rne(b[1]);
  f[6] = bf16_rne(b[2]); f[7] = bf16_rne(b[3]);
  return f;
}

// C[n,b] = sum_i W1[n,i]*x[b,i]; out[b,k] = 1 - 1/(exp2(L*(S))+1) with
// S = b2 + sum_h w2 - sum_h 2*w2/(exp2(L*c + L*b1)+1)   [folded tanh algebra]
// Wave w owns n in [64w,64w+64) -> classifiers {2w,2w+1}. Weights live in regs.
// Register double-buffer: next tile's x loads issued after first barrier,
// consumed at next iteration's pack -> HBM latency overlaps compute.
__global__ __launch_bounds__(256, 4) void fused_mlp8(
    const float* __restrict__ x, const float* __restrict__ W1,
    const float* __restrict__ b1, const float* __restrict__ W2,
    const float* __restrict__ b2, float* __restrict__ out) {

  // x chunks in fragment order: index c = tt*128 + ks*64 + lane, 16B each
  __shared__ short8 xch[512];

  const int tid  = threadIdx.x;
  const int wave = tid >> 6;
  const int lane = tid & 63;
  const int m16  = lane & 15;
  const int q    = lane >> 4;

  // ---- W1 A-fragments: lane holds W1[n=(4w+mt)*16+m16][ks*32+q*8 .. +7]
  short8 w1f[4][2];
#pragma unroll
  for (int mt = 0; mt < 4; ++mt) {
    const int n = (wave * 4 + mt) * 16 + m16;
#pragma unroll
    for (int ks = 0; ks < 2; ++ks) {
      const float* p = W1 + n * 64 + ks * 32 + q * 8;
      w1f[mt][ks] = pack8(*(const f32x4*)p, *(const f32x4*)(p + 4));
    }
  }

  // ---- folded per-lane constants for C-layout rows n0 = (4w+mt)*16 + 4q
  f32x4 kb1[4], w2m[4];
  float sw2[2] = {0.f, 0.f};
#pragma unroll
  for (int mt = 0; mt < 4; ++mt) {
    const int n0 = (wave * 4 + mt) * 16 + q * 4;
    const f32x4 b1x = *(const f32x4*)(b1 + n0);
    const f32x4 w2x = *(const f32x4*)(W2 + n0);
#pragma unroll
    for (int r = 0; r < 4; ++r) {
      kb1[mt][r] = L2E2 * b1x[r];
      w2m[mt][r] = -2.0f * w2x[r];
      sw2[mt >> 1] += w2x[r];
    }
  }
  float KSb[2];
#pragma unroll
  for (int j = 0; j < 2; ++j) {
    float s = sw2[j];
    s += __shfl_xor(s, 16);
    s += __shfl_xor(s, 32);
    KSb[j] = L2E2 * (s + b2[wave * 2 + j]);
  }

  // ---- prefetch first tile (chunks c = tid and c = tid+256; contiguous 4KB/wave)
  f32x4 pf[2][2];
  {
    const long base = (long)blockIdx.x * 64;
#pragma unroll
    for (int cc = 0; cc < 2; ++cc) {
      const int c   = tid + cc * 256;
      const int row = (c >> 7) * 16 + (c & 15);
      const int col = ((c >> 6) & 1) * 32 + ((c & 63) >> 4) * 8;
      const float* p = x + (base + row) * 64 + col;
      pf[cc][0] = *(const f32x4*)p;
      pf[cc][1] = *(const f32x4*)(p + 4);
    }
  }

  for (int it = blockIdx.x; it < ROWTILES; it += GRID) {
    // ---- convert prefetched regs -> LDS
    xch[tid]       = pack8(pf[0][0], pf[0][1]);
    xch[tid + 256] = pack8(pf[1][0], pf[1][1]);
    __syncthreads();

    // ---- issue next tile's loads (consumed at next iteration's pack)
    const int itn = it + GRID;
    if (itn < ROWTILES) {
      const long nbase = (long)itn * 64;
#pragma unroll
      for (int cc = 0; cc < 2; ++cc) {
        const int c   = tid + cc * 256;
        const int row = (c >> 7) * 16 + (c & 15);
        const int col = ((c >> 6) & 1) * 32 + ((c & 63) >> 4) * 8;
        const float* p = x + (nbase + row) * 64 + col;
        pf[cc][0] = *(const f32x4*)p;
        pf[cc][1] = *(const f32x4*)(p + 4);
      }
    }

    const long base = (long)it * 64;
#pragma unroll
    for (int tt = 0; tt < 4; ++tt) {
      const short8 xf0 = xch[(tt * 2 + 0) * 64 + lane];
      const short8 xf1 = xch[(tt * 2 + 1) * 64 + lane];

      f32x4 acc[4];
#pragma unroll
      for (int mt = 0; mt < 4; ++mt) {
        f32x4 z = { 0.f, 0.f, 0.f, 0.f };
        z = __builtin_amdgcn_mfma_f32_16x16x32_bf16(w1f[mt][0], xf0, z, 0, 0, 0);
        z = __builtin_amdgcn_mfma_f32_16x16x32_bf16(w1f[mt][1], xf1, z, 0, 0, 0);
        acc[mt] = z;
      }

      float o0 = 0.f, o1 = 0.f;
#pragma unroll
      for (int j = 0; j < 2; ++j) {
        float P = 0.f;
#pragma unroll
        for (int t = 0; t < 2; ++t) {
          const int mt = j * 2 + t;
#pragma unroll
          for (int r = 0; r < 4; ++r) {
            const float e = __builtin_amdgcn_exp2f(
                __builtin_fmaf(acc[mt][r], L2E2, kb1[mt][r]));
            P = __builtin_fmaf(w2m[mt][r], __builtin_amdgcn_rcpf(e + 1.0f), P);
          }
        }
        P += __shfl_xor(P, 16);
        P += __shfl_xor(P, 32);
        const float arg = __builtin_fmaf(P, L2E2, KSb[j]);
        const float o = 1.0f - __builtin_amdgcn_rcpf(
            __builtin_amdgcn_exp2f(arg) + 1.0f);
        if (j == 0) o0 = o; else o1 = o;
      }

      if (q == 0) {  // 16 lanes store float2 {k=2w,2w+1} for rows tt*16+m16
        float2 st; st.x = o0; st.y = o1;
        *(float2*)(out + (base + tt * 16 + m16) * 8 + wave * 2) = st;
      }
    }
    __syncthreads();
  }
}

extern "C" void kernel_launch(void* const* d_in, const int* in_sizes, int n_in,
                              void* d_out, int out_size, void* d_ws, size_t ws_size,
                              hipStream_t stream) {
  const float* x  = (const float*)d_in[0];
  const float* W1 = (const float*)d_in[1];
  const float* b1 = (const float*)d_in[2];
  const float* W2 = (const float*)d_in[3];
  const float* b2 = (const float*)d_in[4];
  float* out = (float*)d_out;
  fused_mlp8<<<GRID, 256, 0, stream>>>(x, W1, b1, W2, b2, out);
}